// Round 1
// baseline (3604.939 us; speedup 1.0000x reference)
//
#include <hip/hip_runtime.h>
#include <math.h>

#define N_NODES 4096
#define DIM 384
#define N_EDGES 131072
#define N_HEADS 8
#define DH 48
#define N_LAYERS 3

// ======================= CSR build (counting sort by dst) =======================

__global__ void zero_counts_kernel(int* counts, int* cursor) {
  int i = blockIdx.x * blockDim.x + threadIdx.x;
  if (i < N_NODES) { counts[i] = 0; cursor[i] = 0; }
}

__global__ void count_kernel(const int* __restrict__ dst, int* counts) {
  int e = blockIdx.x * blockDim.x + threadIdx.x;
  if (e < N_EDGES) atomicAdd(&counts[dst[e]], 1);
}

__global__ __launch_bounds__(1024) void scan_kernel(const int* __restrict__ counts,
                                                    int* __restrict__ offsets) {
  __shared__ int s[1024];
  int t = threadIdx.x;
  int base = t * 4;
  int c[4];
  int sum = 0;
  #pragma unroll
  for (int i = 0; i < 4; i++) { c[i] = counts[base + i]; sum += c[i]; }
  s[t] = sum;
  __syncthreads();
  for (int off = 1; off < 1024; off <<= 1) {
    int v = (t >= off) ? s[t - off] : 0;
    __syncthreads();
    s[t] += v;
    __syncthreads();
  }
  int excl = s[t] - sum;
  #pragma unroll
  for (int i = 0; i < 4; i++) { offsets[base + i] = excl; excl += c[i]; }
  if (t == 1023) offsets[N_NODES] = s[1023];
}

__global__ void scatter_kernel(const int* __restrict__ dst, const int* __restrict__ src,
                               const int* __restrict__ offsets, int* cursor,
                               int* __restrict__ ssrc) {
  int e = blockIdx.x * blockDim.x + threadIdx.x;
  if (e < N_EDGES) {
    int d = dst[e];
    int pos = atomicAdd(&cursor[d], 1);
    ssrc[offsets[d] + pos] = src[e];
  }
}

// ======================= neighbor aggregation =======================
// agg[i,:] = sum over edges (dst=i) of h[src,:]   (one block per node)

__global__ __launch_bounds__(128) void aggregate_kernel(const float* __restrict__ h,
    const int* __restrict__ ssrc, const int* __restrict__ offsets,
    float* __restrict__ agg) {
  int i = blockIdx.x;
  int t = threadIdx.x;
  int e0 = offsets[i], e1 = offsets[i + 1];
  float a0 = 0.f, a1 = 0.f, a2 = 0.f;
  for (int e = e0; e < e1; e++) {
    const float* row = h + (size_t)ssrc[e] * DIM;
    a0 += row[t];
    a1 += row[t + 128];
    a2 += row[t + 256];
  }
  agg[(size_t)i * DIM + t]       = a0;
  agg[(size_t)i * DIM + t + 128] = a1;
  agg[(size_t)i * DIM + t + 256] = a2;
}

// ======================= fp32 GEMM: C = A @ W^T + epilogue =======================
// A[M,K] row-major, W[Nc,K] row-major. 64x64 tile, BK=16, 256 thr, 4x4 micro.
// MODE 0 (conv):    out0[r,c] = acc + deg[r]*bias[c]
// MODE 1 (qkv):     acc+bias scattered head-major into out0/out1/out2 = q/k/v [H][N][DH]
// MODE 2 (attnout): out0[r,c] = relu(acc + bias[c] + resid[r,c])

template<int MODE>
__global__ __launch_bounds__(256) void gemm_kernel(
    const float* __restrict__ A, const float* __restrict__ W,
    const float* __restrict__ bias, const int* __restrict__ deg,
    const float* __restrict__ resid,
    float* __restrict__ out0, float* __restrict__ out1, float* __restrict__ out2,
    int M, int Nc, int K)
{
  __shared__ float As[16][64];
  __shared__ float Ws[16][64];
  const int tid = threadIdx.x;
  const int tx = tid & 15, ty = tid >> 4;
  const int rowBase = blockIdx.x * 64, colBase = blockIdx.y * 64;
  float acc[4][4] = {};

  const int f  = tid * 4;
  const int lr = f >> 4;    // 0..63
  const int lk = f & 15;    // 0,4,8,12

  for (int k0 = 0; k0 < K; k0 += 16) {
    float4 a4 = *(const float4*)(A + (size_t)(rowBase + lr) * K + k0 + lk);
    As[lk][lr] = a4.x; As[lk+1][lr] = a4.y; As[lk+2][lr] = a4.z; As[lk+3][lr] = a4.w;
    float4 w4 = *(const float4*)(W + (size_t)(colBase + lr) * K + k0 + lk);
    Ws[lk][lr] = w4.x; Ws[lk+1][lr] = w4.y; Ws[lk+2][lr] = w4.z; Ws[lk+3][lr] = w4.w;
    __syncthreads();
    #pragma unroll
    for (int k = 0; k < 16; k++) {
      float4 av = *(const float4*)&As[k][ty * 4];
      float4 wv = *(const float4*)&Ws[k][tx * 4];
      float a[4] = {av.x, av.y, av.z, av.w};
      float w[4] = {wv.x, wv.y, wv.z, wv.w};
      #pragma unroll
      for (int i = 0; i < 4; i++)
        #pragma unroll
        for (int j = 0; j < 4; j++)
          acc[i][j] = fmaf(a[i], w[j], acc[i][j]);
    }
    __syncthreads();
  }

  #pragma unroll
  for (int i = 0; i < 4; i++) {
    int rr = rowBase + ty * 4 + i;
    #pragma unroll
    for (int j = 0; j < 4; j++) {
      int cc = colBase + tx * 4 + j;
      float v = acc[i][j];
      if (MODE == 0) {
        out0[(size_t)rr * Nc + cc] = v + (float)deg[rr] * bias[cc];
      } else if (MODE == 1) {
        v += bias[cc];
        int part = cc / DIM;
        int cm   = cc - part * DIM;
        int head = cm / DH;
        int d    = cm - head * DH;
        float* o = (part == 0) ? out0 : (part == 1) ? out1 : out2;
        o[(size_t)head * (N_NODES * DH) + (size_t)rr * DH + d] = v;
      } else {
        v += bias[cc] + resid[(size_t)rr * Nc + cc];
        out0[(size_t)rr * Nc + cc] = fmaxf(v, 0.f);
      }
    }
  }
}

// ======================= flash attention (fp32, online softmax) =======================
// grid (N/64, H), 256 threads. Q tile 64x48 resident; loop K/V tiles of 64.
// S phase: 16x16 threads, 4x4 micro-tile; P via LDS; PV phase: rows ty*4.., cols tx*3..

__global__ __launch_bounds__(256) void attn_kernel(
    const float* __restrict__ Qg, const float* __restrict__ Kg,
    const float* __restrict__ Vg, float* __restrict__ Og)
{
  __shared__ float Qs[64][52];   // padded to break bank conflicts on row-indexed b128 reads
  __shared__ float Ks[64][52];
  __shared__ float Vt[48][68];   // transposed V: Vt[c][k]
  __shared__ float Ps[64][68];
  __shared__ float mS[64], lS[64], aS[64];

  const int tid = threadIdx.x;
  const int tx = tid & 15, ty = tid >> 4;
  const int head = blockIdx.y;
  const int qBase = blockIdx.x * 64;
  const float* Qh = Qg + (size_t)head * N_NODES * DH;
  const float* Kh = Kg + (size_t)head * N_NODES * DH;
  const float* Vh = Vg + (size_t)head * N_NODES * DH;
  const float scale = 0.14433756729740643f;  // 1/sqrt(48), folded into Q

  for (int f = tid * 4; f < 64 * DH; f += 1024) {
    int r = f / DH, c = f % DH;
    float4 v4 = *(const float4*)(Qh + (size_t)(qBase + r) * DH + c);
    Qs[r][c]   = v4.x * scale; Qs[r][c+1] = v4.y * scale;
    Qs[r][c+2] = v4.z * scale; Qs[r][c+3] = v4.w * scale;
  }
  if (tid < 64) { mS[tid] = -3.0e38f; lS[tid] = 0.f; }
  float Oacc[4][3] = {};
  __syncthreads();

  for (int kb = 0; kb < N_NODES; kb += 64) {
    for (int f = tid * 4; f < 64 * DH; f += 1024) {
      int r = f / DH, c = f % DH;
      float4 kv = *(const float4*)(Kh + (size_t)(kb + r) * DH + c);
      Ks[r][c] = kv.x; Ks[r][c+1] = kv.y; Ks[r][c+2] = kv.z; Ks[r][c+3] = kv.w;
      float4 vv = *(const float4*)(Vh + (size_t)(kb + r) * DH + c);
      Vt[c][r] = vv.x; Vt[c+1][r] = vv.y; Vt[c+2][r] = vv.z; Vt[c+3][r] = vv.w;
    }
    __syncthreads();

    // ---- S = Q K^T (4x4 per thread) ----
    float s[4][4] = {};
    #pragma unroll
    for (int kk = 0; kk < DH; kk += 4) {
      float4 qv[4], kv[4];
      #pragma unroll
      for (int i = 0; i < 4; i++) qv[i] = *(const float4*)&Qs[ty * 4 + i][kk];
      #pragma unroll
      for (int j = 0; j < 4; j++) kv[j] = *(const float4*)&Ks[tx * 4 + j][kk];
      #pragma unroll
      for (int i = 0; i < 4; i++)
        #pragma unroll
        for (int j = 0; j < 4; j++)
          s[i][j] += qv[i].x * kv[j].x + qv[i].y * kv[j].y +
                     qv[i].z * kv[j].z + qv[i].w * kv[j].w;
    }

    // ---- online softmax (row group = 16 tx lanes, contiguous within a wave) ----
    #pragma unroll
    for (int i = 0; i < 4; i++) {
      int row = ty * 4 + i;
      float mx = fmaxf(fmaxf(s[i][0], s[i][1]), fmaxf(s[i][2], s[i][3]));
      #pragma unroll
      for (int off = 1; off < 16; off <<= 1) mx = fmaxf(mx, __shfl_xor(mx, off, 64));
      float mold = mS[row];
      float mnew = fmaxf(mold, mx);
      float rs = 0.f;
      #pragma unroll
      for (int j = 0; j < 4; j++) {
        float p = __expf(s[i][j] - mnew);
        Ps[row][tx * 4 + j] = p;
        rs += p;
      }
      #pragma unroll
      for (int off = 1; off < 16; off <<= 1) rs += __shfl_xor(rs, off, 64);
      if (tx == 0) {
        float al = __expf(mold - mnew);   // exp(-inf)=0 on first tile
        aS[row] = al;
        lS[row] = lS[row] * al + rs;
        mS[row] = mnew;
      }
    }
    __syncthreads();

    // ---- O = O*alpha + P V (rows ty*4.., cols tx*3..) ----
    float al[4];
    #pragma unroll
    for (int i = 0; i < 4; i++) al[i] = aS[ty * 4 + i];
    #pragma unroll
    for (int i = 0; i < 4; i++)
      #pragma unroll
      for (int j = 0; j < 3; j++) Oacc[i][j] *= al[i];
    #pragma unroll
    for (int k4 = 0; k4 < 64; k4 += 4) {
      float4 pv[4], vv[3];
      #pragma unroll
      for (int i = 0; i < 4; i++) pv[i] = *(const float4*)&Ps[ty * 4 + i][k4];
      #pragma unroll
      for (int j = 0; j < 3; j++) vv[j] = *(const float4*)&Vt[tx * 3 + j][k4];
      #pragma unroll
      for (int i = 0; i < 4; i++)
        #pragma unroll
        for (int j = 0; j < 3; j++)
          Oacc[i][j] += pv[i].x * vv[j].x + pv[i].y * vv[j].y +
                        pv[i].z * vv[j].z + pv[i].w * vv[j].w;
    }
    __syncthreads();
  }

  #pragma unroll
  for (int i = 0; i < 4; i++) {
    float linv = 1.f / lS[ty * 4 + i];
    #pragma unroll
    for (int j = 0; j < 3; j++)
      Og[(size_t)(qBase + ty * 4 + i) * DIM + head * DH + tx * 3 + j] = Oacc[i][j] * linv;
  }
}

// ======================= final projection + sigmoid =======================

__global__ __launch_bounds__(256) void out_kernel(const float* __restrict__ h,
    const float* __restrict__ Wout, const float* __restrict__ bout,
    float* __restrict__ out)
{
  int gw = (blockIdx.x * 256 + threadIdx.x) >> 6;  // one wave per node row
  int lane = threadIdx.x & 63;
  if (gw >= N_NODES) return;
  float s = 0.f;
  #pragma unroll
  for (int c = 0; c < 6; c++)
    s += h[(size_t)gw * DIM + lane + c * 64] * Wout[lane + c * 64];
  #pragma unroll
  for (int off = 32; off >= 1; off >>= 1) s += __shfl_xor(s, off, 64);
  if (lane == 0) out[gw] = 1.f / (1.f + __expf(-(s + bout[0])));
}

// ======================= launch =======================

extern "C" void kernel_launch(void* const* d_in, const int* in_sizes, int n_in,
                              void* d_out, int out_size, void* d_ws, size_t ws_size,
                              hipStream_t stream)
{
  const float* node_emb = (const float*)d_in[0];
  const int*   edge_index = (const int*)d_in[1];
  const float* W_conv = (const float*)d_in[2];
  const float* b_conv = (const float*)d_in[3];
  const float* W_in   = (const float*)d_in[4];
  const float* b_in   = (const float*)d_in[5];
  const float* W_ao   = (const float*)d_in[6];
  const float* b_ao   = (const float*)d_in[7];
  const float* W_out  = (const float*)d_in[8];
  const float* b_out  = (const float*)d_in[9];
  float* out = (float*)d_out;

  const size_t ND = (size_t)N_NODES * DIM;
  float* h      = (float*)d_ws;
  float* agg    = h + ND;
  float* hnew   = agg + ND;
  float* q      = hnew + ND;
  float* k      = q + ND;
  float* v      = k + ND;
  float* attn_o = v + ND;
  int* counts   = (int*)(attn_o + ND);
  int* offsets  = counts + N_NODES;
  int* cursor   = offsets + N_NODES + 1;
  int* ssrc     = cursor + N_NODES;

  const int* dst = edge_index;             // edge_index[0,:]
  const int* src = edge_index + N_EDGES;   // edge_index[1,:]

  zero_counts_kernel<<<(N_NODES + 255) / 256, 256, 0, stream>>>(counts, cursor);
  count_kernel<<<N_EDGES / 256, 256, 0, stream>>>(dst, counts);
  scan_kernel<<<1, 1024, 0, stream>>>(counts, offsets);
  scatter_kernel<<<N_EDGES / 256, 256, 0, stream>>>(dst, src, offsets, cursor, ssrc);
  hipMemcpyAsync(h, node_emb, ND * sizeof(float), hipMemcpyDeviceToDevice, stream);

  for (int l = 0; l < N_LAYERS; l++) {
    aggregate_kernel<<<N_NODES, 128, 0, stream>>>(h, ssrc, offsets, agg);
    gemm_kernel<0><<<dim3(64, 6), 256, 0, stream>>>(
        agg, W_conv + (size_t)l * DIM * DIM, b_conv + (size_t)l * DIM, counts, nullptr,
        hnew, nullptr, nullptr, N_NODES, DIM, DIM);
    gemm_kernel<1><<<dim3(64, 18), 256, 0, stream>>>(
        hnew, W_in, b_in, nullptr, nullptr,
        q, k, v, N_NODES, 3 * DIM, DIM);
    attn_kernel<<<dim3(64, 8), 256, 0, stream>>>(q, k, v, attn_o);
    gemm_kernel<2><<<dim3(64, 6), 256, 0, stream>>>(
        attn_o, W_ao, b_ao, nullptr, h,
        h, nullptr, nullptr, N_NODES, DIM, DIM);
  }
  out_kernel<<<1024, 256, 0, stream>>>(h, W_out, b_out, out);
}

// Round 3
// 880.176 us; speedup vs baseline: 4.0957x; 4.0957x over previous
//
#include <hip/hip_runtime.h>
#include <math.h>

#define N_NODES 4096
#define DIM 384
#define N_EDGES 131072
#define N_HEADS 8
#define DH 48
#define N_LAYERS 3

typedef short v4s __attribute__((ext_vector_type(4)));
typedef short v8s __attribute__((ext_vector_type(8)));
typedef float v4f __attribute__((ext_vector_type(4)));

#define MFMA32(A, B, C) __builtin_amdgcn_mfma_f32_16x16x32_bf16(A, B, C, 0, 0, 0)
#define MFMA16(A, B, C) __builtin_amdgcn_mfma_f32_16x16x16bf16_1k(A, B, C, 0, 0, 0)
#define EXP2F(x) __builtin_exp2f(x)

// ======================= CSR build (counting sort by dst) =======================

__global__ void zero_counts_kernel(int* counts, int* cursor) {
  int i = blockIdx.x * blockDim.x + threadIdx.x;
  if (i < N_NODES) { counts[i] = 0; cursor[i] = 0; }
}

__global__ void count_kernel(const int* __restrict__ dst, int* counts) {
  int e = blockIdx.x * blockDim.x + threadIdx.x;
  if (e < N_EDGES) atomicAdd(&counts[dst[e]], 1);
}

__global__ __launch_bounds__(1024) void scan_kernel(const int* __restrict__ counts,
                                                    int* __restrict__ offsets) {
  __shared__ int s[1024];
  int t = threadIdx.x;
  int base = t * 4;
  int c[4];
  int sum = 0;
  #pragma unroll
  for (int i = 0; i < 4; i++) { c[i] = counts[base + i]; sum += c[i]; }
  s[t] = sum;
  __syncthreads();
  for (int off = 1; off < 1024; off <<= 1) {
    int v = (t >= off) ? s[t - off] : 0;
    __syncthreads();
    s[t] += v;
    __syncthreads();
  }
  int excl = s[t] - sum;
  #pragma unroll
  for (int i = 0; i < 4; i++) { offsets[base + i] = excl; excl += c[i]; }
  if (t == 1023) offsets[N_NODES] = s[1023];
}

__global__ void scatter_kernel(const int* __restrict__ dst, const int* __restrict__ src,
                               const int* __restrict__ offsets, int* cursor,
                               int* __restrict__ ssrc) {
  int e = blockIdx.x * blockDim.x + threadIdx.x;
  if (e < N_EDGES) {
    int d = dst[e];
    int pos = atomicAdd(&cursor[d], 1);
    ssrc[offsets[d] + pos] = src[e];
  }
}

// ======================= neighbor aggregation =======================

__global__ __launch_bounds__(128) void aggregate_kernel(const float* __restrict__ h,
    const int* __restrict__ ssrc, const int* __restrict__ offsets,
    float* __restrict__ agg) {
  int i = blockIdx.x;
  int t = threadIdx.x;
  int e0 = offsets[i], e1 = offsets[i + 1];
  float a0 = 0.f, a1 = 0.f, a2 = 0.f;
  for (int e = e0; e < e1; e++) {
    const float* row = h + (size_t)ssrc[e] * DIM;
    a0 += row[t];
    a1 += row[t + 128];
    a2 += row[t + 256];
  }
  agg[(size_t)i * DIM + t]       = a0;
  agg[(size_t)i * DIM + t + 128] = a1;
  agg[(size_t)i * DIM + t + 256] = a2;
}

// ======================= bf16 split helpers =======================

__device__ __forceinline__ void bsplit(float v, ushort& hi, ushort& lo) {
  unsigned b = __float_as_uint(v);
  unsigned hb = b & 0xFFFF0000u;
  hi = (ushort)(b >> 16);
  float r = v - __uint_as_float(hb);
  lo = (ushort)(__float_as_uint(r) >> 16);
}

// pack hi16 of (a,b) into one dword (a in low half), and same for residuals
__device__ __forceinline__ void psplit2(float a, float b, unsigned& hi, unsigned& lo) {
  hi = __builtin_amdgcn_perm(__float_as_uint(b), __float_as_uint(a), 0x07060302u);
  float ra = a - __uint_as_float(hi << 16);
  float rb = b - __uint_as_float(hi & 0xFFFF0000u);
  lo = __builtin_amdgcn_perm(__float_as_uint(rb), __float_as_uint(ra), 0x07060302u);
}

// ======================= fp32 GEMM: C = A @ W^T + epilogue =======================
// MODE 0 (conv):    out0[r,c] = acc + deg[r]*bias[c]
// MODE 2 (attnout): out0[r,c] = relu(acc + bias[c] + resid[r,c])

template<int MODE>
__global__ __launch_bounds__(256) void gemm_kernel(
    const float* __restrict__ A, const float* __restrict__ W,
    const float* __restrict__ bias, const int* __restrict__ deg,
    const float* __restrict__ resid,
    float* __restrict__ out0, int M, int Nc, int K)
{
  __shared__ float As[16][64];
  __shared__ float Ws[16][64];
  const int tid = threadIdx.x;
  const int tx = tid & 15, ty = tid >> 4;
  const int rowBase = blockIdx.x * 64, colBase = blockIdx.y * 64;
  float acc[4][4] = {};

  const int f  = tid * 4;
  const int lr = f >> 4;
  const int lk = f & 15;

  for (int k0 = 0; k0 < K; k0 += 16) {
    float4 a4 = *(const float4*)(A + (size_t)(rowBase + lr) * K + k0 + lk);
    As[lk][lr] = a4.x; As[lk+1][lr] = a4.y; As[lk+2][lr] = a4.z; As[lk+3][lr] = a4.w;
    float4 w4 = *(const float4*)(W + (size_t)(colBase + lr) * K + k0 + lk);
    Ws[lk][lr] = w4.x; Ws[lk+1][lr] = w4.y; Ws[lk+2][lr] = w4.z; Ws[lk+3][lr] = w4.w;
    __syncthreads();
    #pragma unroll
    for (int k = 0; k < 16; k++) {
      float4 av = *(const float4*)&As[k][ty * 4];
      float4 wv = *(const float4*)&Ws[k][tx * 4];
      float a[4] = {av.x, av.y, av.z, av.w};
      float w[4] = {wv.x, wv.y, wv.z, wv.w};
      #pragma unroll
      for (int i = 0; i < 4; i++)
        #pragma unroll
        for (int j = 0; j < 4; j++)
          acc[i][j] = fmaf(a[i], w[j], acc[i][j]);
    }
    __syncthreads();
  }

  #pragma unroll
  for (int i = 0; i < 4; i++) {
    int rr = rowBase + ty * 4 + i;
    #pragma unroll
    for (int j = 0; j < 4; j++) {
      int cc = colBase + tx * 4 + j;
      float v = acc[i][j];
      if (MODE == 0) {
        out0[(size_t)rr * Nc + cc] = v + (float)deg[rr] * bias[cc];
      } else {
        v += bias[cc] + resid[(size_t)rr * Nc + cc];
        out0[(size_t)rr * Nc + cc] = fmaxf(v, 0.f);
      }
    }
  }
}

// ======================= qkv GEMM with split-bf16 epilogue =======================
// q scaled by log2(e)/sqrt(48); outputs q/k as [H][N][48] hi/lo, v as [H][48][N] hi/lo.

__global__ __launch_bounds__(256) void qkv_gemm_kernel(
    const float* __restrict__ A, const float* __restrict__ W,
    const float* __restrict__ bias,
    ushort* __restrict__ qhi, ushort* __restrict__ qlo,
    ushort* __restrict__ khi, ushort* __restrict__ klo,
    ushort* __restrict__ vthi, ushort* __restrict__ vtlo)
{
  const int K = DIM;
  __shared__ float As[16][64];
  __shared__ float Ws[16][64];
  const int tid = threadIdx.x;
  const int tx = tid & 15, ty = tid >> 4;
  const int rowBase = blockIdx.x * 64, colBase = blockIdx.y * 64;
  float acc[4][4] = {};

  const int f  = tid * 4;
  const int lr = f >> 4;
  const int lk = f & 15;

  for (int k0 = 0; k0 < K; k0 += 16) {
    float4 a4 = *(const float4*)(A + (size_t)(rowBase + lr) * K + k0 + lk);
    As[lk][lr] = a4.x; As[lk+1][lr] = a4.y; As[lk+2][lr] = a4.z; As[lk+3][lr] = a4.w;
    float4 w4 = *(const float4*)(W + (size_t)(colBase + lr) * K + k0 + lk);
    Ws[lk][lr] = w4.x; Ws[lk+1][lr] = w4.y; Ws[lk+2][lr] = w4.z; Ws[lk+3][lr] = w4.w;
    __syncthreads();
    #pragma unroll
    for (int k = 0; k < 16; k++) {
      float4 av = *(const float4*)&As[k][ty * 4];
      float4 wv = *(const float4*)&Ws[k][tx * 4];
      float a[4] = {av.x, av.y, av.z, av.w};
      float w[4] = {wv.x, wv.y, wv.z, wv.w};
      #pragma unroll
      for (int i = 0; i < 4; i++)
        #pragma unroll
        for (int j = 0; j < 4; j++)
          acc[i][j] = fmaf(a[i], w[j], acc[i][j]);
    }
    __syncthreads();
  }

  const float cq = 0.20823507f;  // log2(e)/sqrt(48)
  const int cc0 = colBase + tx * 4;
  const int part = cc0 / DIM;
  const int cm = cc0 - part * DIM;
  const int hd = cm / DH;
  const int d0 = cm - hd * DH;

  if (part < 2) {
    ushort* oh = (part == 0) ? qhi : khi;
    ushort* ol = (part == 0) ? qlo : klo;
    const float sc = (part == 0) ? cq : 1.0f;
    #pragma unroll
    for (int i = 0; i < 4; i++) {
      int rr = rowBase + ty * 4 + i;
      ushort4 H, L;
      float v0 = (acc[i][0] + bias[cc0 + 0]) * sc;
      float v1 = (acc[i][1] + bias[cc0 + 1]) * sc;
      float v2 = (acc[i][2] + bias[cc0 + 2]) * sc;
      float v3 = (acc[i][3] + bias[cc0 + 3]) * sc;
      bsplit(v0, H.x, L.x); bsplit(v1, H.y, L.y);
      bsplit(v2, H.z, L.z); bsplit(v3, H.w, L.w);
      size_t off = ((size_t)hd * N_NODES + rr) * DH + d0;
      *(ushort4*)(oh + off) = H;
      *(ushort4*)(ol + off) = L;
    }
  } else {
    int rr0 = rowBase + ty * 4;
    #pragma unroll
    for (int j = 0; j < 4; j++) {
      int d = d0 + j;
      float b = bias[cc0 + j];
      ushort4 H, L;
      float v0 = acc[0][j] + b, v1 = acc[1][j] + b, v2 = acc[2][j] + b, v3 = acc[3][j] + b;
      bsplit(v0, H.x, L.x); bsplit(v1, H.y, L.y);
      bsplit(v2, H.z, L.z); bsplit(v3, H.w, L.w);
      size_t off = ((size_t)hd * DH + d) * N_NODES + rr0;
      *(ushort4*)(vthi + off) = H;
      *(ushort4*)(vtlo + off) = L;
    }
  }
}

// ======================= MFMA flash attention (split-bf16 ~fp32 accuracy) ======
// grid (H=8, N/64), 256 thr = 4 waves. Wave w owns kcol slice [kb+16w, kb+16w+16).
// S^T = K·Q^T via mfma (C-frag: col=lane&15=qrow, row=quad*4+reg=kcol) — this
// C-frag IS the B-operand (P^T) fragment for O^T = V^T·P^T (16x16x16). No LDS
// in the main loop; one 4-way merge at the end.

__global__ __launch_bounds__(256, 2) void attn_kernel(
    const ushort* __restrict__ qhi, const ushort* __restrict__ qlo,
    const ushort* __restrict__ khi, const ushort* __restrict__ klo,
    const ushort* __restrict__ vthi, const ushort* __restrict__ vtlo,
    float* __restrict__ attn_o)
{
  const int head = blockIdx.x;
  const int qBase = blockIdx.y * 64;
  const int tid = threadIdx.x;
  const int w = tid >> 6;
  const int lane = tid & 63;
  const int li = lane & 15, quad = lane >> 4;

  const size_t headQK = (size_t)head * N_NODES * DH;
  const size_t headV  = (size_t)head * DH * N_NODES;

  // ---- resident Q fragments (B-operand: n=lane&15 -> qrow, k -> dh) ----
  v8s q0h[4], q0l[4];
  v4s q1h[4], q1l[4];
  #pragma unroll
  for (int qt = 0; qt < 4; qt++) {
    const ushort* qr = qhi + headQK + (size_t)(qBase + 16 * qt + li) * DH;
    const ushort* ql = qlo + headQK + (size_t)(qBase + 16 * qt + li) * DH;
    q0h[qt] = *(const v8s*)(qr + quad * 8);
    q0l[qt] = *(const v8s*)(ql + quad * 8);
    q1h[qt] = *(const v4s*)(qr + 32 + quad * 4);
    q1l[qt] = *(const v4s*)(ql + 32 + quad * 4);
  }

  v4f ot[3][4];
  #pragma unroll
  for (int mt = 0; mt < 3; mt++)
    #pragma unroll
    for (int qt = 0; qt < 4; qt++)
      ot[mt][qt] = (v4f){0.f, 0.f, 0.f, 0.f};
  float m2[4] = {-3.0e38f, -3.0e38f, -3.0e38f, -3.0e38f};
  float lsum[4] = {0.f, 0.f, 0.f, 0.f};

  const ushort* kh_p = khi + headQK + (size_t)(16 * w + li) * DH;
  const ushort* kl_p = klo + headQK + (size_t)(16 * w + li) * DH;
  const ushort* vh_p = vthi + headV + (size_t)li * N_NODES + 16 * w + quad * 4;
  const ushort* vl_p = vtlo + headV + (size_t)li * N_NODES + 16 * w + quad * 4;

  v8s nk0h = *(const v8s*)(kh_p + quad * 8);
  v8s nk0l = *(const v8s*)(kl_p + quad * 8);
  v4s nk1h = *(const v4s*)(kh_p + 32 + quad * 4);
  v4s nk1l = *(const v4s*)(kl_p + 32 + quad * 4);
  v4s nvh[3], nvl[3];
  #pragma unroll
  for (int mt = 0; mt < 3; mt++) {
    nvh[mt] = *(const v4s*)(vh_p + (size_t)mt * 16 * N_NODES);
    nvl[mt] = *(const v4s*)(vl_p + (size_t)mt * 16 * N_NODES);
  }

  for (int kb = 0; kb < N_NODES; kb += 64) {
    v8s ck0h = nk0h, ck0l = nk0l;
    v4s ck1h = nk1h, ck1l = nk1l;
    v4s cvh[3], cvl[3];
    #pragma unroll
    for (int mt = 0; mt < 3; mt++) { cvh[mt] = nvh[mt]; cvl[mt] = nvl[mt]; }

    if (kb + 64 < N_NODES) {
      kh_p += 64 * DH; kl_p += 64 * DH; vh_p += 64; vl_p += 64;
      nk0h = *(const v8s*)(kh_p + quad * 8);
      nk0l = *(const v8s*)(kl_p + quad * 8);
      nk1h = *(const v4s*)(kh_p + 32 + quad * 4);
      nk1l = *(const v4s*)(kl_p + 32 + quad * 4);
      #pragma unroll
      for (int mt = 0; mt < 3; mt++) {
        nvh[mt] = *(const v4s*)(vh_p + (size_t)mt * 16 * N_NODES);
        nvl[mt] = *(const v4s*)(vl_p + (size_t)mt * 16 * N_NODES);
      }
    }

    // ---- S^T = K·Q^T (scores pre-scaled to log2 domain via q) ----
    v4f s[4];
    #pragma unroll
    for (int qt = 0; qt < 4; qt++) {
      v4f acc = (v4f){0.f, 0.f, 0.f, 0.f};
      acc = MFMA32(ck0h, q0h[qt], acc);
      acc = MFMA32(ck0l, q0h[qt], acc);
      acc = MFMA32(ck0h, q0l[qt], acc);
      acc = MFMA16(ck1h, q1h[qt], acc);
      acc = MFMA16(ck1l, q1h[qt], acc);
      acc = MFMA16(ck1h, q1l[qt], acc);
      s[qt] = acc;
    }

    // ---- online softmax over this wave's 16 kcols ----
    v4s pH[4], pL[4];
    float al[4];
    #pragma unroll
    for (int qt = 0; qt < 4; qt++) {
      float mx = fmaxf(fmaxf(s[qt][0], s[qt][1]), fmaxf(s[qt][2], s[qt][3]));
      mx = fmaxf(mx, __shfl_xor(mx, 16, 64));
      mx = fmaxf(mx, __shfl_xor(mx, 32, 64));
      float mn = fmaxf(m2[qt], mx);
      float a = EXP2F(m2[qt] - mn);
      m2[qt] = mn;
      al[qt] = a;
      float p0 = EXP2F(s[qt][0] - mn);
      float p1 = EXP2F(s[qt][1] - mn);
      float p2 = EXP2F(s[qt][2] - mn);
      float p3 = EXP2F(s[qt][3] - mn);
      float rs = (p0 + p1) + (p2 + p3);
      rs += __shfl_xor(rs, 16, 64);
      rs += __shfl_xor(rs, 32, 64);
      lsum[qt] = lsum[qt] * a + rs;
      unsigned h0, l0, h1, l1;
      psplit2(p0, p1, h0, l0);
      psplit2(p2, p3, h1, l1);
      union { uint2 u; v4s v; } uh, ul;
      uh.u = make_uint2(h0, h1);
      ul.u = make_uint2(l0, l1);
      pH[qt] = uh.v;
      pL[qt] = ul.v;
    }

    bool resc = (al[0] != 1.f) | (al[1] != 1.f) | (al[2] != 1.f) | (al[3] != 1.f);
    if (__any(resc)) {
      #pragma unroll
      for (int mt = 0; mt < 3; mt++)
        #pragma unroll
        for (int qt = 0; qt < 4; qt++)
          ot[mt][qt] *= al[qt];
    }

    // ---- O^T += V^T · P^T ----
    #pragma unroll
    for (int mt = 0; mt < 3; mt++) {
      #pragma unroll
      for (int qt = 0; qt < 4; qt++) {
        v4f acc = ot[mt][qt];
        acc = MFMA16(cvh[mt], pH[qt], acc);
        acc = MFMA16(cvl[mt], pH[qt], acc);
        acc = MFMA16(cvh[mt], pL[qt], acc);
        ot[mt][qt] = acc;
      }
    }
  }

  // ---- merge the 4 per-wave partials ----
  __shared__ float Obuf[4][64][49];
  __shared__ float Mbuf[4][4][16];
  __shared__ float Lbuf[4][4][16];

  #pragma unroll
  for (int mt = 0; mt < 3; mt++)
    #pragma unroll
    for (int qt = 0; qt < 4; qt++)
      #pragma unroll
      for (int r = 0; r < 4; r++)
        Obuf[w][16 * qt + li][16 * mt + 4 * quad + r] = ot[mt][qt][r];
  if (quad == 0) {
    #pragma unroll
    for (int qt = 0; qt < 4; qt++) {
      Mbuf[w][qt][li] = m2[qt];
      Lbuf[w][qt][li] = lsum[qt];
    }
  }
  __syncthreads();

  // wave w outputs qrows [16w, 16w+16); lane: row=li, cols quad*12..+11
  float M = Mbuf[0][w][li];
  #pragma unroll
  for (int sw = 1; sw < 4; sw++) M = fmaxf(M, Mbuf[sw][w][li]);
  float sc[4];
  float lt = 0.f;
  #pragma unroll
  for (int sw = 0; sw < 4; sw++) {
    sc[sw] = EXP2F(Mbuf[sw][w][li] - M);
    lt += Lbuf[sw][w][li] * sc[sw];
  }
  float inv = 1.f / lt;
  int orow = 16 * w + li;
  float* outp = attn_o + (size_t)(qBase + orow) * DIM + head * DH + quad * 12;
  #pragma unroll
  for (int g = 0; g < 3; g++) {
    float a0 = 0.f, a1 = 0.f, a2 = 0.f, a3 = 0.f;
    #pragma unroll
    for (int sw = 0; sw < 4; sw++) {
      const float* ob = &Obuf[sw][orow][quad * 12 + g * 4];
      a0 += ob[0] * sc[sw];
      a1 += ob[1] * sc[sw];
      a2 += ob[2] * sc[sw];
      a3 += ob[3] * sc[sw];
    }
    float4 o4 = make_float4(a0 * inv, a1 * inv, a2 * inv, a3 * inv);
    *(float4*)(outp + g * 4) = o4;
  }
}

// ======================= final projection + sigmoid =======================

__global__ __launch_bounds__(256) void out_kernel(const float* __restrict__ h,
    const float* __restrict__ Wout, const float* __restrict__ bout,
    float* __restrict__ out)
{
  int gw = (blockIdx.x * 256 + threadIdx.x) >> 6;
  int lane = threadIdx.x & 63;
  if (gw >= N_NODES) return;
  float s = 0.f;
  #pragma unroll
  for (int c = 0; c < 6; c++)
    s += h[(size_t)gw * DIM + lane + c * 64] * Wout[lane + c * 64];
  #pragma unroll
  for (int off = 32; off >= 1; off >>= 1) s += __shfl_xor(s, off, 64);
  if (lane == 0) out[gw] = 1.f / (1.f + __expf(-(s + bout[0])));
}

// ======================= launch =======================

extern "C" void kernel_launch(void* const* d_in, const int* in_sizes, int n_in,
                              void* d_out, int out_size, void* d_ws, size_t ws_size,
                              hipStream_t stream)
{
  const float* node_emb = (const float*)d_in[0];
  const int*   edge_index = (const int*)d_in[1];
  const float* W_conv = (const float*)d_in[2];
  const float* b_conv = (const float*)d_in[3];
  const float* W_in   = (const float*)d_in[4];
  const float* b_in   = (const float*)d_in[5];
  const float* W_ao   = (const float*)d_in[6];
  const float* b_ao   = (const float*)d_in[7];
  const float* W_out  = (const float*)d_in[8];
  const float* b_out  = (const float*)d_in[9];
  float* out = (float*)d_out;

  const size_t ND = (size_t)N_NODES * DIM;   // == 8*4096*48
  float* h      = (float*)d_ws;
  float* agg    = h + ND;        // reused as attn_o
  float* hnew   = agg + ND;
  ushort* qhi   = (ushort*)(hnew + ND);
  ushort* qlo   = qhi + ND;
  ushort* khi   = qlo + ND;
  ushort* klo   = khi + ND;
  ushort* vthi  = klo + ND;
  ushort* vtlo  = vthi + ND;
  int* counts   = (int*)(vtlo + ND);
  int* offsets  = counts + N_NODES;
  int* cursor   = offsets + N_NODES + 1;
  int* ssrc     = cursor + N_NODES;

  const int* dst = edge_index;
  const int* src = edge_index + N_EDGES;

  zero_counts_kernel<<<(N_NODES + 255) / 256, 256, 0, stream>>>(counts, cursor);
  count_kernel<<<N_EDGES / 256, 256, 0, stream>>>(dst, counts);
  scan_kernel<<<1, 1024, 0, stream>>>(counts, offsets);
  scatter_kernel<<<N_EDGES / 256, 256, 0, stream>>>(dst, src, offsets, cursor, ssrc);
  (void)hipMemcpyAsync(h, node_emb, ND * sizeof(float), hipMemcpyDeviceToDevice, stream);

  for (int l = 0; l < N_LAYERS; l++) {
    aggregate_kernel<<<N_NODES, 128, 0, stream>>>(h, ssrc, offsets, agg);
    gemm_kernel<0><<<dim3(64, 6), 256, 0, stream>>>(
        agg, W_conv + (size_t)l * DIM * DIM, b_conv + (size_t)l * DIM, counts, nullptr,
        hnew, N_NODES, DIM, DIM);
    qkv_gemm_kernel<<<dim3(64, 18), 256, 0, stream>>>(
        hnew, W_in, b_in, qhi, qlo, khi, klo, vthi, vtlo);
    attn_kernel<<<dim3(8, 64), 256, 0, stream>>>(
        qhi, qlo, khi, klo, vthi, vtlo, agg);
    gemm_kernel<2><<<dim3(64, 6), 256, 0, stream>>>(
        agg, W_ao, b_ao, nullptr, h,
        h, N_NODES, DIM, DIM);
  }
  out_kernel<<<1024, 256, 0, stream>>>(h, W_out, b_out, out);
}